// Round 1
// baseline (225.032 us; speedup 1.0000x reference)
//
#include <hip/hip_runtime.h>
#include <math.h>

// LearnableVisitEncoder: per-vocab precompute of phi + attention logit,
// then per-visit softmax-pool + rho.
//
// Pipeline (all fp32 — output threshold is fp32-tight):
//   K1: H1 = silu(emb @ W1 + b1)            [20000,128]
//   K2: H2 = silu(H1  @ W2 + b2)            [20000,128]
//   K3: G  = tanh(H2  @ Wa1 + ba1)          [20000,128]  (into H1 buffer)
//   K4: L[r] = G[r] . wa2 + ba2             [20000]
//   K5: per visit: softmax(mask(L[ids])), HP = sum a_c * H2[id_c]  [16384,128]
//   K6: T1 = silu(HP @ Wr1 + br1)           [16384,128]  (into H1 buffer)
//   K7: out = T1 @ Wr2 + br2                [16384,128]

#define DIM 128
#define MT 80   // rows per block in mlp_layer (250 blocks for 20000 rows)

// Y[M,128] = act(X[M,128] @ W[128,128] + b[128]);  ACT: 0=none, 1=silu, 2=tanh
template<int ACT>
__global__ __launch_bounds__(256) void mlp_layer(
    const float* __restrict__ X, const float* __restrict__ W,
    const float* __restrict__ b, float* __restrict__ Y, int M)
{
  __shared__ float sX[MT][DIM + 4];   // +4 pad: breaks row-wise bank aliasing
  __shared__ float sW[DIM][DIM];
  __shared__ float sB[DIM];

  const int tid = threadIdx.x;
  const int m0 = blockIdx.x * MT;

  // stage W: 4096 float4, 16 per thread
  {
    const float4* Wv = (const float4*)W;
    float4* sWv = (float4*)&sW[0][0];
#pragma unroll
    for (int i = 0; i < 16; ++i) sWv[tid + i * 256] = Wv[tid + i * 256];
    if (tid < DIM) sB[tid] = b[tid];
  }
  // stage X rows [m0, m0+MT): 2560 float4, 10 per thread; zero-fill OOB rows
  {
    const float4* Xv = (const float4*)(X + (size_t)m0 * DIM);
#pragma unroll
    for (int i = 0; i < 10; ++i) {
      int idx = tid + i * 256;          // 0..2559
      int r = idx >> 5, c4 = idx & 31;  // row, float4-col
      float4 v = make_float4(0.f, 0.f, 0.f, 0.f);
      if (m0 + r < M) v = Xv[(size_t)r * 32 + c4];
      ((float4*)&sX[r][0])[c4] = v;     // row stride 132 floats = 528 B, 16B-aligned
    }
  }
  __syncthreads();

  const int tc = tid & 15;   // 16 col groups of 8
  const int tr = tid >> 4;   // 16 row groups of 5
  const int c0 = tc * 8;
  const int r0 = tr * 5;

  float acc[5][8];
#pragma unroll
  for (int i = 0; i < 5; ++i)
#pragma unroll
    for (int j = 0; j < 8; ++j) acc[i][j] = 0.f;

#pragma unroll 8
  for (int k = 0; k < DIM; ++k) {
    float aa[5];
#pragma unroll
    for (int i = 0; i < 5; ++i) aa[i] = sX[r0 + i][k];
    float4 w0 = ((const float4*)&sW[k][0])[tc * 2];
    float4 w1 = ((const float4*)&sW[k][0])[tc * 2 + 1];
    float wj[8] = {w0.x, w0.y, w0.z, w0.w, w1.x, w1.y, w1.z, w1.w};
#pragma unroll
    for (int i = 0; i < 5; ++i)
#pragma unroll
      for (int j = 0; j < 8; ++j) acc[i][j] = fmaf(aa[i], wj[j], acc[i][j]);
  }

#pragma unroll
  for (int i = 0; i < 5; ++i) {
    int r = m0 + r0 + i;
    if (r < M) {
      float o[8];
#pragma unroll
      for (int j = 0; j < 8; ++j) {
        float v = acc[i][j] + sB[c0 + j];
        if (ACT == 1) v = v * (1.0f / (1.0f + expf(-v)));   // silu
        else if (ACT == 2) v = tanhf(v);
        o[j] = v;
      }
      float* yp = Y + (size_t)r * DIM + c0;
      ((float4*)yp)[0] = make_float4(o[0], o[1], o[2], o[3]);
      ((float4*)yp)[1] = make_float4(o[4], o[5], o[6], o[7]);
    }
  }
}

// L[r] = G[r,:] . wa2 + ba2   (one wave per row, 4 rows/block)
__global__ __launch_bounds__(256) void rowdot_kernel(
    const float* __restrict__ G, const float* __restrict__ wa2,
    const float* __restrict__ ba2, float* __restrict__ L, int M)
{
  int wid = threadIdx.x >> 6, lane = threadIdx.x & 63;
  int r = blockIdx.x * 4 + wid;
  if (r >= M) return;
  const float* g = G + (size_t)r * DIM;
  float s = fmaf(g[lane], wa2[lane], g[lane + 64] * wa2[lane + 64]);
#pragma unroll
  for (int m = 32; m; m >>= 1) s += __shfl_xor(s, m, 64);
  if (lane == 0) L[r] = s + ba2[0];
}

// Per-visit: masked softmax over 48 code logits, then HP[v] = sum_c a_c * H2[id_c]
// one wave per visit, 4 visits per block
__global__ __launch_bounds__(256) void pool_kernel(
    const int* __restrict__ ids, const float* __restrict__ L,
    const float* __restrict__ H2, float* __restrict__ HP, int V)
{
  int wid = threadIdx.x >> 6, lane = threadIdx.x & 63;
  int v = blockIdx.x * 4 + wid;
  if (v >= V) return;

  int id = 0;
  float lg = -3.4e38f;
  if (lane < 48) {
    id = ids[(size_t)v * 48 + lane];
    if (id != 0) lg = L[id];       // PAD_IDX==0 masked out
  }
  float mx = lg;
#pragma unroll
  for (int m = 32; m; m >>= 1) mx = fmaxf(mx, __shfl_xor(mx, m, 64));
  float e = (lg > -3.0e38f) ? expf(lg - mx) : 0.f;
  float s = e;
#pragma unroll
  for (int m = 32; m; m >>= 1) s += __shfl_xor(s, m, 64);
  float a = e / s;

  float2 acc = make_float2(0.f, 0.f);
#pragma unroll 4
  for (int c = 0; c < 48; ++c) {
    float ac = __shfl(a, c, 64);     // wave-uniform
    int idc = __shfl(id, c, 64);
    if (ac > 0.f) {                  // uniform branch; pads have a==0 exactly
      float2 h = ((const float2*)(H2 + (size_t)idc * DIM))[lane];
      acc.x = fmaf(ac, h.x, acc.x);
      acc.y = fmaf(ac, h.y, acc.y);
    }
  }
  ((float2*)(HP + (size_t)v * DIM))[lane] = acc;
}

extern "C" void kernel_launch(void* const* d_in, const int* in_sizes, int n_in,
                              void* d_out, int out_size, void* d_ws, size_t ws_size,
                              hipStream_t stream)
{
  const int*   ids = (const int*)  d_in[0];
  const float* emb = (const float*)d_in[1];
  const float* W1  = (const float*)d_in[2];
  const float* b1  = (const float*)d_in[3];
  const float* W2  = (const float*)d_in[4];
  const float* b2  = (const float*)d_in[5];
  const float* Wa1 = (const float*)d_in[6];
  const float* ba1 = (const float*)d_in[7];
  const float* wa2 = (const float*)d_in[8];
  const float* ba2 = (const float*)d_in[9];
  const float* Wr1 = (const float*)d_in[10];
  const float* br1 = (const float*)d_in[11];
  const float* Wr2 = (const float*)d_in[12];
  const float* br2 = (const float*)d_in[13];
  float* out = (float*)d_out;

  const int VOCAB = 20000, V = 16384;

  // workspace layout (floats); total ~29 MB
  float* H1 = (float*)d_ws;                      // 20000*128 (reused for G, T1)
  float* H2 = H1 + (size_t)VOCAB * DIM;          // 20000*128
  float* L  = H2 + (size_t)VOCAB * DIM;          // 20000 (padded to 20096)
  float* HP = L + 20096;                         // 16384*128

  dim3 blk(256);
  const int gV = VOCAB / MT;                     // 250 exact
  const int gM = (V + MT - 1) / MT;              // 205

  mlp_layer<1><<<gV, blk, 0, stream>>>(emb, W1, b1, H1, VOCAB);
  mlp_layer<1><<<gV, blk, 0, stream>>>(H1, W2, b2, H2, VOCAB);
  mlp_layer<2><<<gV, blk, 0, stream>>>(H2, Wa1, ba1, H1, VOCAB);     // G -> H1
  rowdot_kernel<<<VOCAB / 4, blk, 0, stream>>>(H1, wa2, ba2, L, VOCAB);
  pool_kernel<<<V / 4, blk, 0, stream>>>(ids, L, H2, HP, V);
  mlp_layer<1><<<gM, blk, 0, stream>>>(HP, Wr1, br1, H1, V);         // T1 -> H1
  mlp_layer<0><<<gM, blk, 0, stream>>>(H1, Wr2, br2, out, V);
}

// Round 2
// 206.215 us; speedup vs baseline: 1.0912x; 1.0912x over previous
//
#include <hip/hip_runtime.h>
#include <math.h>

// LearnableVisitEncoder — 3-kernel pipeline, all fp32:
//   A vocab_fused : emb[20000,128] -> H2 = silu(silu(emb@W1+b1)@W2+b2)  (stored)
//                   L[r] = tanh(H2@Wa1+ba1) . wa2 + ba2                 (stored)
//   B pool        : per visit masked softmax over L[ids], HP = sum a_c H2[id_c]
//   C rho_fused   : out = silu(HP@Wr1+br1)@Wr2 + br2
//
// GEMM template: 256 thr = 32 col-groups (4 cols) x 8 row-groups (4 rows),
// MT=32 rows/block (20000=625*32, 16384=512*32 — exact, no guards).
// X tiles ping-pong in LDS (2 x 16.9 KB -> 4 blocks/CU); W streamed from
// global (64 KB, L1/L2-hot) — keeps the LDS pipe for X broadcasts only.

#define DIM 128
#define MT 32
#define LDP (DIM + 4)   // LDS row stride: 132 floats, keeps 16B alignment

__device__ __forceinline__ float silu_f(float v) {
  return v / (1.0f + expf(-v));
}

// stage MT x 128 fp32 rows (contiguous global) into LDS tile
__device__ __forceinline__ void stage32(const float* __restrict__ src,
                                        float (*dst)[LDP], int tid) {
  const float4* s = (const float4*)src;
#pragma unroll
  for (int t = 0; t < 4; ++t) {
    int idx = tid + t * 256;          // 0..1023 float4s = 32 rows x 32
    int r = idx >> 5, c4 = idx & 31;
    *(float4*)&dst[r][c4 * 4] = s[idx];
  }
}

#define FMAROW(i, xs, wv)                                                   \
  acc[i][0] = fmaf(xs, wv.x, acc[i][0]);                                    \
  acc[i][1] = fmaf(xs, wv.y, acc[i][1]);                                    \
  acc[i][2] = fmaf(xs, wv.z, acc[i][2]);                                    \
  acc[i][3] = fmaf(xs, wv.w, acc[i][3]);
#define FMAK(comp, wv)                                                      \
  FMAROW(0, x0.comp, wv) FMAROW(1, x1.comp, wv)                             \
  FMAROW(2, x2.comp, wv) FMAROW(3, x3.comp, wv)

// acc[4][4] = sIn[r0..r0+3][:] @ W[:][c0..c0+3]
__device__ __forceinline__ void gemm32(const float (*sIn)[LDP],
                                       const float* __restrict__ Wg,
                                       int tc, int tr, float acc[4][4]) {
#pragma unroll
  for (int i = 0; i < 4; ++i)
#pragma unroll
    for (int j = 0; j < 4; ++j) acc[i][j] = 0.f;
  const float4* Wv = (const float4*)Wg;  // W[k][c]: float4 index k*32 + tc
  const int r0 = tr * 4;
#pragma unroll 4
  for (int k0 = 0; k0 < DIM; k0 += 4) {
    float4 x0 = *(const float4*)&sIn[r0 + 0][k0];   // broadcast reads
    float4 x1 = *(const float4*)&sIn[r0 + 1][k0];
    float4 x2 = *(const float4*)&sIn[r0 + 2][k0];
    float4 x3 = *(const float4*)&sIn[r0 + 3][k0];
    float4 w0 = Wv[(k0 + 0) * 32 + tc];             // L1-hot stream
    float4 w1 = Wv[(k0 + 1) * 32 + tc];
    float4 w2 = Wv[(k0 + 2) * 32 + tc];
    float4 w3 = Wv[(k0 + 3) * 32 + tc];
    FMAK(x, w0) FMAK(y, w1) FMAK(z, w2) FMAK(w, w3)
  }
}

// ---------------- Kernel A: vocab side, fully fused ----------------
__global__ __launch_bounds__(256, 4) void vocab_fused(
    const float* __restrict__ emb, const float* __restrict__ W1,
    const float* __restrict__ b1, const float* __restrict__ W2,
    const float* __restrict__ b2, const float* __restrict__ Wa1,
    const float* __restrict__ ba1, const float* __restrict__ wa2,
    const float* __restrict__ ba2, float* __restrict__ H2,
    float* __restrict__ L) {
  __shared__ float sA[MT][LDP], sB[MT][LDP];
  const int tid = threadIdx.x;
  const int tc = tid & 31, tr = tid >> 5;
  const int r0 = tr * 4, c0 = tc * 4;
  const int m0 = blockIdx.x * MT;

  stage32(emb + (size_t)m0 * DIM, sA, tid);
  __syncthreads();

  float acc[4][4];
  // layer 1: silu(emb@W1+b1) -> sB
  gemm32(sA, W1, tc, tr, acc);
  {
    float4 bv = ((const float4*)b1)[tc];
#pragma unroll
    for (int i = 0; i < 4; ++i) {
      float4 o;
      o.x = silu_f(acc[i][0] + bv.x);
      o.y = silu_f(acc[i][1] + bv.y);
      o.z = silu_f(acc[i][2] + bv.z);
      o.w = silu_f(acc[i][3] + bv.w);
      *(float4*)&sB[r0 + i][c0] = o;
    }
  }
  __syncthreads();
  // layer 2: silu(sB@W2+b2) -> sA + global H2
  gemm32(sB, W2, tc, tr, acc);
  {
    float4 bv = ((const float4*)b2)[tc];
#pragma unroll
    for (int i = 0; i < 4; ++i) {
      float4 o;
      o.x = silu_f(acc[i][0] + bv.x);
      o.y = silu_f(acc[i][1] + bv.y);
      o.z = silu_f(acc[i][2] + bv.z);
      o.w = silu_f(acc[i][3] + bv.w);
      *(float4*)&sA[r0 + i][c0] = o;
      *(float4*)&H2[(size_t)(m0 + r0 + i) * DIM + c0] = o;
    }
  }
  __syncthreads();
  // layer 3: tanh(sA@Wa1+ba1) . wa2 + ba2 -> L  (rowdot fused)
  gemm32(sA, Wa1, tc, tr, acc);
  {
    float4 bv = ((const float4*)ba1)[tc];
    float4 wv = ((const float4*)wa2)[tc];
    float bb2 = ba2[0];
#pragma unroll
    for (int i = 0; i < 4; ++i) {
      float g0 = tanhf(acc[i][0] + bv.x);
      float g1 = tanhf(acc[i][1] + bv.y);
      float g2 = tanhf(acc[i][2] + bv.z);
      float g3 = tanhf(acc[i][3] + bv.w);
      float p = fmaf(g0, wv.x, fmaf(g1, wv.y, fmaf(g2, wv.z, g3 * wv.w)));
#pragma unroll
      for (int m = 16; m; m >>= 1) p += __shfl_xor(p, m, 64);  // over 32 tc lanes
      if (tc == 0) L[m0 + r0 + i] = p + bb2;
    }
  }
}

// ---------------- Kernel B: softmax-pool ----------------
// one wave per visit, 4 visits/block; 2 codes per iter via float4/lane
__global__ __launch_bounds__(256, 8) void pool_kernel(
    const int* __restrict__ ids, const float* __restrict__ L,
    const float* __restrict__ H2, float* __restrict__ HP) {
  const int wid = threadIdx.x >> 6, lane = threadIdx.x & 63;
  const int v = blockIdx.x * 4 + wid;

  int id = 0;
  float lg = -3.4e38f;
  if (lane < 48) {
    id = ids[(size_t)v * 48 + lane];
    if (id != 0) lg = L[id];   // PAD_IDX==0 masked
  }
  float mx = lg;
#pragma unroll
  for (int m = 32; m; m >>= 1) mx = fmaxf(mx, __shfl_xor(mx, m, 64));
  float e = (lg > -3.0e38f) ? expf(lg - mx) : 0.f;
  float s = e;
#pragma unroll
  for (int m = 32; m; m >>= 1) s += __shfl_xor(s, m, 64);
  const float a = e / s;           // pads: exactly 0

  const int half = lane >> 5, li = lane & 31;
  float4 acc = make_float4(0.f, 0.f, 0.f, 0.f);
#pragma unroll 8
  for (int c = 0; c < 24; ++c) {   // lanes 0-31: even codes, 32-63: odd
    const int cc = 2 * c + half;
    const float ac = __shfl(a, cc, 64);
    const int idc = __shfl(id, cc, 64);
    const float4 h = ((const float4*)(H2 + (size_t)idc * DIM))[li];
    acc.x = fmaf(ac, h.x, acc.x);  // pad: ac==0 exactly -> no-op
    acc.y = fmaf(ac, h.y, acc.y);
    acc.z = fmaf(ac, h.z, acc.z);
    acc.w = fmaf(ac, h.w, acc.w);
  }
  acc.x += __shfl_xor(acc.x, 32, 64);
  acc.y += __shfl_xor(acc.y, 32, 64);
  acc.z += __shfl_xor(acc.z, 32, 64);
  acc.w += __shfl_xor(acc.w, 32, 64);
  if (half == 0) ((float4*)(HP + (size_t)v * DIM))[li] = acc;
}

// ---------------- Kernel C: rho, fused 2 layers ----------------
__global__ __launch_bounds__(256, 4) void rho_fused(
    const float* __restrict__ HP, const float* __restrict__ Wr1,
    const float* __restrict__ br1, const float* __restrict__ Wr2,
    const float* __restrict__ br2, float* __restrict__ out) {
  __shared__ float sA[MT][LDP], sB[MT][LDP];
  const int tid = threadIdx.x;
  const int tc = tid & 31, tr = tid >> 5;
  const int r0 = tr * 4, c0 = tc * 4;
  const int m0 = blockIdx.x * MT;

  stage32(HP + (size_t)m0 * DIM, sA, tid);
  __syncthreads();

  float acc[4][4];
  gemm32(sA, Wr1, tc, tr, acc);
  {
    float4 bv = ((const float4*)br1)[tc];
#pragma unroll
    for (int i = 0; i < 4; ++i) {
      float4 o;
      o.x = silu_f(acc[i][0] + bv.x);
      o.y = silu_f(acc[i][1] + bv.y);
      o.z = silu_f(acc[i][2] + bv.z);
      o.w = silu_f(acc[i][3] + bv.w);
      *(float4*)&sB[r0 + i][c0] = o;
    }
  }
  __syncthreads();
  gemm32(sB, Wr2, tc, tr, acc);
  {
    float4 bv = ((const float4*)br2)[tc];
#pragma unroll
    for (int i = 0; i < 4; ++i) {
      float4 o;
      o.x = acc[i][0] + bv.x;
      o.y = acc[i][1] + bv.y;
      o.z = acc[i][2] + bv.z;
      o.w = acc[i][3] + bv.w;
      *(float4*)&out[(size_t)(m0 + r0 + i) * DIM + c0] = o;
    }
  }
}

extern "C" void kernel_launch(void* const* d_in, const int* in_sizes, int n_in,
                              void* d_out, int out_size, void* d_ws,
                              size_t ws_size, hipStream_t stream) {
  const int*   ids = (const int*)  d_in[0];
  const float* emb = (const float*)d_in[1];
  const float* W1  = (const float*)d_in[2];
  const float* b1  = (const float*)d_in[3];
  const float* W2  = (const float*)d_in[4];
  const float* b2  = (const float*)d_in[5];
  const float* Wa1 = (const float*)d_in[6];
  const float* ba1 = (const float*)d_in[7];
  const float* wa2 = (const float*)d_in[8];
  const float* ba2 = (const float*)d_in[9];
  const float* Wr1 = (const float*)d_in[10];
  const float* br1 = (const float*)d_in[11];
  const float* Wr2 = (const float*)d_in[12];
  const float* br2 = (const float*)d_in[13];
  float* out = (float*)d_out;

  const int VOCAB = 20000, V = 16384;

  float* H2 = (float*)d_ws;                       // 20000*128
  float* L  = H2 + (size_t)VOCAB * DIM;           // 20000
  float* HP = L + VOCAB;                          // 16384*128 (16B-aligned)

  vocab_fused<<<VOCAB / MT, 256, 0, stream>>>(emb, W1, b1, W2, b2, Wa1, ba1,
                                              wa2, ba2, H2, L);
  pool_kernel<<<V / 4, 256, 0, stream>>>(ids, L, H2, HP);
  rho_fused<<<V / MT, 256, 0, stream>>>(HP, Wr1, br1, Wr2, br2, out);
}

// Round 3
// 194.588 us; speedup vs baseline: 1.1565x; 1.0598x over previous
//
#include <hip/hip_runtime.h>
#include <math.h>

// LearnableVisitEncoder — 3-kernel pipeline, all fp32:
//   A vocab_fused : emb[20000,128] -> H2 = silu(silu(emb@W1+b1)@W2+b2) (stored)
//                   L[r] = tanh(H2@Wa1+ba1) . wa2 + ba2                (stored)
//   B pool        : per visit masked softmax over L[ids], HP = sum a_c H2[id_c]
//   C rho_fused   : out = silu(HP@Wr1+br1)@Wr2 + br2
//
// GEMM: wave-column-split. Each of the 4 waves owns a 32-col slice of W for
// ALL 32 rows of the block tile: per-wave W footprint = 16 KB/layer
// (L1-resident stream), no W duplication across waves (64 KB/block/layer).
// Per-thread 4x4 tile: lane&7 -> col-group (4 cols), lane>>3 -> row-group
// (4 rows). Inter-layer __syncthreads makes the col-split composable.

#define DIM 128
#define MT 32
#define LDP (DIM + 4)   // LDS row stride 132 floats (528 B): 16B-aligned

__device__ __forceinline__ float silu_f(float v) {
  return v / (1.0f + expf(-v));
}

// stage MT x 128 fp32 rows (contiguous global) into LDS tile
__device__ __forceinline__ void stage32(const float* __restrict__ src,
                                        float (*dst)[LDP], int tid) {
  const float4* s = (const float4*)src;
#pragma unroll
  for (int t = 0; t < 4; ++t) {
    int idx = tid + t * 256;          // 0..1023 float4s = 32 rows x 32
    int r = idx >> 5, c4 = idx & 31;
    *(float4*)&dst[r][c4 * 4] = s[idx];
  }
}

#define FMAROW(i, xs, wv)                                                   \
  acc[i][0] = fmaf(xs, wv.x, acc[i][0]);                                    \
  acc[i][1] = fmaf(xs, wv.y, acc[i][1]);                                    \
  acc[i][2] = fmaf(xs, wv.z, acc[i][2]);                                    \
  acc[i][3] = fmaf(xs, wv.w, acc[i][3]);
#define FMAK(comp, wv)                                                      \
  FMAROW(0, x0.comp, wv) FMAROW(1, x1.comp, wv)                             \
  FMAROW(2, x2.comp, wv) FMAROW(3, x3.comp, wv)

// acc[4][4] = sIn[r0..r0+3][:] @ W[:][4*cg..4*cg+3]
__device__ __forceinline__ void gemm_wave(const float (*sIn)[LDP],
                                          const float* __restrict__ Wg,
                                          int cg, int r0, float acc[4][4]) {
#pragma unroll
  for (int i = 0; i < 4; ++i)
#pragma unroll
    for (int j = 0; j < 4; ++j) acc[i][j] = 0.f;
  const float4* Wv = (const float4*)Wg;  // W[k][c]: float4 index k*32 + cg
#pragma unroll 4
  for (int k0 = 0; k0 < DIM; k0 += 4) {
    float4 x0 = *(const float4*)&sIn[r0 + 0][k0];  // 8 distinct rows/wave
    float4 x1 = *(const float4*)&sIn[r0 + 1][k0];
    float4 x2 = *(const float4*)&sIn[r0 + 2][k0];
    float4 x3 = *(const float4*)&sIn[r0 + 3][k0];
    float4 w0 = Wv[(k0 + 0) * 32 + cg];            // 8 consec float4s/wave:
    float4 w1 = Wv[(k0 + 1) * 32 + cg];            // 128B request, L1-hot
    float4 w2 = Wv[(k0 + 2) * 32 + cg];
    float4 w3 = Wv[(k0 + 3) * 32 + cg];
    FMAK(x, w0) FMAK(y, w1) FMAK(z, w2) FMAK(w, w3)
  }
}

// ---------------- Kernel A: vocab side, fully fused ----------------
__global__ __launch_bounds__(256, 4) void vocab_fused(
    const float* __restrict__ emb, const float* __restrict__ W1,
    const float* __restrict__ b1, const float* __restrict__ W2,
    const float* __restrict__ b2, const float* __restrict__ Wa1,
    const float* __restrict__ ba1, const float* __restrict__ wa2,
    const float* __restrict__ ba2, float* __restrict__ H2,
    float* __restrict__ L) {
  __shared__ float sA[MT][LDP], sB[MT][LDP];
  __shared__ float sP[4][MT];
  const int tid = threadIdx.x;
  const int wid = tid >> 6, lane = tid & 63;
  const int cg = wid * 8 + (lane & 7);  // float4-col index 0..31
  const int c0 = cg * 4;
  const int r0 = (lane >> 3) * 4;
  const int m0 = blockIdx.x * MT;

  stage32(emb + (size_t)m0 * DIM, sA, tid);
  __syncthreads();

  float acc[4][4];
  // layer 1: silu(emb@W1+b1) -> sB  (this wave's 32-col slice)
  gemm_wave(sA, W1, cg, r0, acc);
  {
    float4 bv = ((const float4*)b1)[cg];
#pragma unroll
    for (int i = 0; i < 4; ++i) {
      float4 o;
      o.x = silu_f(acc[i][0] + bv.x);
      o.y = silu_f(acc[i][1] + bv.y);
      o.z = silu_f(acc[i][2] + bv.z);
      o.w = silu_f(acc[i][3] + bv.w);
      *(float4*)&sB[r0 + i][c0] = o;
    }
  }
  __syncthreads();
  // layer 2: silu(sB@W2+b2) -> sA + global H2
  gemm_wave(sB, W2, cg, r0, acc);
  {
    float4 bv = ((const float4*)b2)[cg];
#pragma unroll
    for (int i = 0; i < 4; ++i) {
      float4 o;
      o.x = silu_f(acc[i][0] + bv.x);
      o.y = silu_f(acc[i][1] + bv.y);
      o.z = silu_f(acc[i][2] + bv.z);
      o.w = silu_f(acc[i][3] + bv.w);
      *(float4*)&sA[r0 + i][c0] = o;
      *(float4*)&H2[(size_t)(m0 + r0 + i) * DIM + c0] = o;
    }
  }
  __syncthreads();
  // layer 3: tanh(sA@Wa1+ba1) . wa2 + ba2 -> L (rowdot fused)
  gemm_wave(sA, Wa1, cg, r0, acc);
  {
    float4 bv = ((const float4*)ba1)[cg];
    float4 wv = ((const float4*)wa2)[cg];
#pragma unroll
    for (int i = 0; i < 4; ++i) {
      float g0 = tanhf(acc[i][0] + bv.x);
      float g1 = tanhf(acc[i][1] + bv.y);
      float g2 = tanhf(acc[i][2] + bv.z);
      float g3 = tanhf(acc[i][3] + bv.w);
      float p = fmaf(g0, wv.x, fmaf(g1, wv.y, fmaf(g2, wv.z, g3 * wv.w)));
#pragma unroll
      for (int m = 1; m <= 4; m <<= 1) p += __shfl_xor(p, m, 64);  // 8 cgs
      if ((lane & 7) == 0) sP[wid][r0 + i] = p;
    }
  }
  __syncthreads();
  if (tid < MT)
    L[m0 + tid] = sP[0][tid] + sP[1][tid] + sP[2][tid] + sP[3][tid] + ba2[0];
}

// ---------------- Kernel B: softmax-pool ----------------
// one wave per visit, 4 visits/block; 2 codes per iter via float4/lane
__global__ __launch_bounds__(256, 8) void pool_kernel(
    const int* __restrict__ ids, const float* __restrict__ L,
    const float* __restrict__ H2, float* __restrict__ HP) {
  const int wid = threadIdx.x >> 6, lane = threadIdx.x & 63;
  const int v = blockIdx.x * 4 + wid;

  int id = 0;
  float lg = -3.4e38f;
  if (lane < 48) {
    id = ids[(size_t)v * 48 + lane];
    if (id != 0) lg = L[id];   // PAD_IDX==0 masked
  }
  float mx = lg;
#pragma unroll
  for (int m = 32; m; m >>= 1) mx = fmaxf(mx, __shfl_xor(mx, m, 64));
  float e = (lg > -3.0e38f) ? expf(lg - mx) : 0.f;
  float s = e;
#pragma unroll
  for (int m = 32; m; m >>= 1) s += __shfl_xor(s, m, 64);
  const float a = e / s;           // pads: exactly 0

  const int half = lane >> 5, li = lane & 31;
  float4 acc = make_float4(0.f, 0.f, 0.f, 0.f);
#pragma unroll 8
  for (int c = 0; c < 24; ++c) {   // lanes 0-31: even codes, 32-63: odd
    const int cc = 2 * c + half;
    const float ac = __shfl(a, cc, 64);
    const int idc = __shfl(id, cc, 64);
    const float4 h = ((const float4*)(H2 + (size_t)idc * DIM))[li];
    acc.x = fmaf(ac, h.x, acc.x);  // pad: ac==0 exactly -> no-op
    acc.y = fmaf(ac, h.y, acc.y);
    acc.z = fmaf(ac, h.z, acc.z);
    acc.w = fmaf(ac, h.w, acc.w);
  }
  acc.x += __shfl_xor(acc.x, 32, 64);
  acc.y += __shfl_xor(acc.y, 32, 64);
  acc.z += __shfl_xor(acc.z, 32, 64);
  acc.w += __shfl_xor(acc.w, 32, 64);
  if (half == 0) ((float4*)(HP + (size_t)v * DIM))[li] = acc;
}

// ---------------- Kernel C: rho, fused 2 layers ----------------
__global__ __launch_bounds__(256, 4) void rho_fused(
    const float* __restrict__ HP, const float* __restrict__ Wr1,
    const float* __restrict__ br1, const float* __restrict__ Wr2,
    const float* __restrict__ br2, float* __restrict__ out) {
  __shared__ float sA[MT][LDP], sB[MT][LDP];
  const int tid = threadIdx.x;
  const int wid = tid >> 6, lane = tid & 63;
  const int cg = wid * 8 + (lane & 7);
  const int c0 = cg * 4;
  const int r0 = (lane >> 3) * 4;
  const int m0 = blockIdx.x * MT;

  stage32(HP + (size_t)m0 * DIM, sA, tid);
  __syncthreads();

  float acc[4][4];
  gemm_wave(sA, Wr1, cg, r0, acc);
  {
    float4 bv = ((const float4*)br1)[cg];
#pragma unroll
    for (int i = 0; i < 4; ++i) {
      float4 o;
      o.x = silu_f(acc[i][0] + bv.x);
      o.y = silu_f(acc[i][1] + bv.y);
      o.z = silu_f(acc[i][2] + bv.z);
      o.w = silu_f(acc[i][3] + bv.w);
      *(float4*)&sB[r0 + i][c0] = o;
    }
  }
  __syncthreads();
  gemm_wave(sB, Wr2, cg, r0, acc);
  {
    float4 bv = ((const float4*)br2)[cg];
#pragma unroll
    for (int i = 0; i < 4; ++i) {
      float4 o;
      o.x = acc[i][0] + bv.x;
      o.y = acc[i][1] + bv.y;
      o.z = acc[i][2] + bv.z;
      o.w = acc[i][3] + bv.w;
      *(float4*)&out[(size_t)(m0 + r0 + i) * DIM + c0] = o;
    }
  }
}

extern "C" void kernel_launch(void* const* d_in, const int* in_sizes, int n_in,
                              void* d_out, int out_size, void* d_ws,
                              size_t ws_size, hipStream_t stream) {
  const int*   ids = (const int*)  d_in[0];
  const float* emb = (const float*)d_in[1];
  const float* W1  = (const float*)d_in[2];
  const float* b1  = (const float*)d_in[3];
  const float* W2  = (const float*)d_in[4];
  const float* b2  = (const float*)d_in[5];
  const float* Wa1 = (const float*)d_in[6];
  const float* ba1 = (const float*)d_in[7];
  const float* wa2 = (const float*)d_in[8];
  const float* ba2 = (const float*)d_in[9];
  const float* Wr1 = (const float*)d_in[10];
  const float* br1 = (const float*)d_in[11];
  const float* Wr2 = (const float*)d_in[12];
  const float* br2 = (const float*)d_in[13];
  float* out = (float*)d_out;

  const int VOCAB = 20000, V = 16384;

  float* H2 = (float*)d_ws;                       // 20000*128
  float* L  = H2 + (size_t)VOCAB * DIM;           // 20000
  float* HP = L + VOCAB;                          // 16384*128 (16B-aligned)

  vocab_fused<<<VOCAB / MT, 256, 0, stream>>>(emb, W1, b1, W2, b2, Wa1, ba1,
                                              wa2, ba2, H2, L);
  pool_kernel<<<V / 4, 256, 0, stream>>>(ids, L, H2, HP);
  rho_fused<<<V / MT, 256, 0, stream>>>(HP, Wr1, br1, Wr2, br2, out);
}